// Round 2
// baseline (9997.548 us; speedup 1.0000x reference)
//
#include <hip/hip_runtime.h>
#include <hip/hip_bf16.h>
#include <math.h>

#define NTOK 4096
#define DM   1024
#define DI   2048
#define DS   16
#define NH   8
#define DHD  128
#define NEXP 4
#define DFF  4096
#define LSEQ 2048

static __device__ __forceinline__ float sigmoid_f(float x){ return 1.f/(1.f+__expf(-x)); }
static __device__ __forceinline__ float silu_f(float x){ return x*sigmoid_f(x); }
static __device__ __forceinline__ float bu2f(ushort u){ return __uint_as_float(((unsigned)u)<<16); }
static __device__ __forceinline__ ushort f2bu(float f){
  unsigned u = __float_as_uint(f);
  u += 0x7FFFu + ((u>>16)&1u);           // round-to-nearest-even
  return (ushort)(u>>16);
}
static __device__ __forceinline__ void stc(float* p, float v){ *p = v; }
static __device__ __forceinline__ void stc(ushort* p, float v){ *p = f2bu(v); }

// ---------------- RMSNorm: fp32 in -> bf16 out, one block per token ----------------
__global__ __launch_bounds__(256) void k_rms(const float* __restrict__ x,
                                             const float* __restrict__ w,
                                             ushort* __restrict__ o){
  int tok = blockIdx.x, t = threadIdx.x;
  float4 v = *(const float4*)(x + (size_t)tok*DM + t*4);
  float ss = v.x*v.x+v.y*v.y+v.z*v.z+v.w*v.w;
  __shared__ float red[256];
  red[t]=ss; __syncthreads();
  for(int s=128;s>0;s>>=1){ if(t<s) red[t]+=red[t+s]; __syncthreads(); }
  float nrm = rsqrtf(red[0]*(1.f/DM)+1e-6f);
  float4 wv = *(const float4*)(w + t*4);
  ushort4 ov;
  ov.x=f2bu(v.x*nrm*wv.x); ov.y=f2bu(v.y*nrm*wv.y);
  ov.z=f2bu(v.z*nrm*wv.z); ov.w=f2bu(v.w*nrm*wv.w);
  *(ushort4*)(o + (size_t)tok*DM + t*4) = ov;
}

// ---------------- GEMM: A bf16 (lda), B fp32 [K][N], C templated, fused epilogues ----
// EPI 0: C=acc | 1: C=aux1[idx]+aux2[col]*acc | 2: C+=aux2[col]*acc
// EPI 3: C=relu(acc+aux1[col]) | 4: C+=aux2[col]*aux1[row*4+eidx]*acc
template<typename TC, int EPI>
__global__ __launch_bounds__(256) void k_gemm(const ushort* __restrict__ A,
    const float* __restrict__ B, TC* __restrict__ C,
    int M, int N, int K, int lda,
    const float* __restrict__ aux1, const float* __restrict__ aux2, int eidx){
  __shared__ float As[16][65];
  __shared__ float Bs[16][65];
  int t = threadIdx.x;
  int bm = blockIdx.y<<6, bn = blockIdx.x<<6;
  int tm = (t>>4)<<2, tn = (t&15)<<2;
  int ar = t>>2,  ak  = (t&3)<<2;
  int bk = t>>4,  bn4 = (t&15)<<2;
  float acc[4][4];
  #pragma unroll
  for(int i=0;i<4;i++)
    #pragma unroll
    for(int j=0;j<4;j++) acc[i][j]=0.f;
  for(int k0=0;k0<K;k0+=16){
    ushort4 av = *(const ushort4*)(A + (size_t)(bm+ar)*lda + k0 + ak);
    As[ak  ][ar]=bu2f(av.x); As[ak+1][ar]=bu2f(av.y);
    As[ak+2][ar]=bu2f(av.z); As[ak+3][ar]=bu2f(av.w);
    int col = bn + bn4;
    const float* bp = B + (size_t)(k0+bk)*N + col;
    float4 bv;
    if(col+3 < N){ bv = *(const float4*)bp; }
    else {
      bv.x=(col  <N)?bp[0]:0.f; bv.y=(col+1<N)?bp[1]:0.f;
      bv.z=(col+2<N)?bp[2]:0.f; bv.w=(col+3<N)?bp[3]:0.f;
    }
    Bs[bk][bn4]=bv.x; Bs[bk][bn4+1]=bv.y; Bs[bk][bn4+2]=bv.z; Bs[bk][bn4+3]=bv.w;
    __syncthreads();
    #pragma unroll
    for(int k=0;k<16;k++){
      float a0=As[k][tm],a1=As[k][tm+1],a2=As[k][tm+2],a3=As[k][tm+3];
      float b0=Bs[k][tn],b1=Bs[k][tn+1],b2=Bs[k][tn+2],b3=Bs[k][tn+3];
      acc[0][0]+=a0*b0; acc[0][1]+=a0*b1; acc[0][2]+=a0*b2; acc[0][3]+=a0*b3;
      acc[1][0]+=a1*b0; acc[1][1]+=a1*b1; acc[1][2]+=a1*b2; acc[1][3]+=a1*b3;
      acc[2][0]+=a2*b0; acc[2][1]+=a2*b1; acc[2][2]+=a2*b2; acc[2][3]+=a2*b3;
      acc[3][0]+=a3*b0; acc[3][1]+=a3*b1; acc[3][2]+=a3*b2; acc[3][3]+=a3*b3;
    }
    __syncthreads();
  }
  #pragma unroll
  for(int i=0;i<4;i++){
    int row = bm+tm+i;
    #pragma unroll
    for(int j=0;j<4;j++){
      int col = bn+tn+j;
      if(col>=N) continue;
      size_t idx = (size_t)row*N+col;
      float a = acc[i][j], val = a;
      if(EPI==1)      val = aux1[idx] + aux2[col]*a;
      else if(EPI==2) val = ((const float*)C)[idx] + aux2[col]*a;
      else if(EPI==3){ float s=a+aux1[col]; val = s>0.f?s:0.f; }
      else if(EPI==4) val = ((const float*)C)[idx] + aux2[col]*aux1[(size_t)row*4+eidx]*a;
      stc(&C[idx], val);
    }
  }
}

// ---------------- dual-B GEMM for MoE w1/w2: C = bf16(silu(A@B1) * (A@B2)) ----------
__global__ __launch_bounds__(256) void k_gemm2(const ushort* __restrict__ A,
    const float* __restrict__ B1, const float* __restrict__ B2,
    ushort* __restrict__ C, int M, int N, int K, int lda){
  __shared__ float As[16][65];
  __shared__ float B1s[16][65];
  __shared__ float B2s[16][65];
  int t = threadIdx.x;
  int bm = blockIdx.y<<6, bn = blockIdx.x<<6;
  int tm = (t>>4)<<2, tn = (t&15)<<2;
  int ar = t>>2,  ak  = (t&3)<<2;
  int bk = t>>4,  bn4 = (t&15)<<2;
  float acc1[4][4], acc2[4][4];
  #pragma unroll
  for(int i=0;i<4;i++)
    #pragma unroll
    for(int j=0;j<4;j++){ acc1[i][j]=0.f; acc2[i][j]=0.f; }
  for(int k0=0;k0<K;k0+=16){
    ushort4 av = *(const ushort4*)(A + (size_t)(bm+ar)*lda + k0 + ak);
    As[ak  ][ar]=bu2f(av.x); As[ak+1][ar]=bu2f(av.y);
    As[ak+2][ar]=bu2f(av.z); As[ak+3][ar]=bu2f(av.w);
    int col = bn + bn4;
    float4 b1 = *(const float4*)(B1 + (size_t)(k0+bk)*N + col);
    float4 b2 = *(const float4*)(B2 + (size_t)(k0+bk)*N + col);
    B1s[bk][bn4]=b1.x; B1s[bk][bn4+1]=b1.y; B1s[bk][bn4+2]=b1.z; B1s[bk][bn4+3]=b1.w;
    B2s[bk][bn4]=b2.x; B2s[bk][bn4+1]=b2.y; B2s[bk][bn4+2]=b2.z; B2s[bk][bn4+3]=b2.w;
    __syncthreads();
    #pragma unroll
    for(int k=0;k<16;k++){
      float a0=As[k][tm],a1=As[k][tm+1],a2=As[k][tm+2],a3=As[k][tm+3];
      float c0=B1s[k][tn],c1=B1s[k][tn+1],c2=B1s[k][tn+2],c3=B1s[k][tn+3];
      float d0=B2s[k][tn],d1=B2s[k][tn+1],d2=B2s[k][tn+2],d3=B2s[k][tn+3];
      acc1[0][0]+=a0*c0; acc1[0][1]+=a0*c1; acc1[0][2]+=a0*c2; acc1[0][3]+=a0*c3;
      acc1[1][0]+=a1*c0; acc1[1][1]+=a1*c1; acc1[1][2]+=a1*c2; acc1[1][3]+=a1*c3;
      acc1[2][0]+=a2*c0; acc1[2][1]+=a2*c1; acc1[2][2]+=a2*c2; acc1[2][3]+=a2*c3;
      acc1[3][0]+=a3*c0; acc1[3][1]+=a3*c1; acc1[3][2]+=a3*c2; acc1[3][3]+=a3*c3;
      acc2[0][0]+=a0*d0; acc2[0][1]+=a0*d1; acc2[0][2]+=a0*d2; acc2[0][3]+=a0*d3;
      acc2[1][0]+=a1*d0; acc2[1][1]+=a1*d1; acc2[1][2]+=a1*d2; acc2[1][3]+=a1*d3;
      acc2[2][0]+=a2*d0; acc2[2][1]+=a2*d1; acc2[2][2]+=a2*d2; acc2[2][3]+=a2*d3;
      acc2[3][0]+=a3*d0; acc2[3][1]+=a3*d1; acc2[3][2]+=a3*d2; acc2[3][3]+=a3*d3;
    }
    __syncthreads();
  }
  #pragma unroll
  for(int i=0;i<4;i++){
    int row = bm+tm+i;
    #pragma unroll
    for(int j=0;j<4;j++){
      int col = bn+tn+j;
      size_t idx = (size_t)row*N+col;
      C[idx] = f2bu(silu_f(acc1[i][j]) * acc2[i][j]);
    }
  }
}

// ---------------- depthwise conv (pad 2 left, 1 right) + SiLU, bf16 io ----------------
__global__ __launch_bounds__(256) void k_conv(const ushort* __restrict__ XZ,
    const float* __restrict__ cw, const float* __restrict__ cb,
    ushort* __restrict__ XC){
  int idx = blockIdx.x*256 + threadIdx.x;       // NTOK*DI
  int d = idx & (DI-1);
  int tok = idx >> 11;
  int tt = tok & (LSEQ-1);
  int b = tok >> 11;
  float acc = cb[d];
  #pragma unroll
  for(int k=0;k<4;k++){
    int t2 = tt + k - 2;
    if((unsigned)t2 < LSEQ)
      acc += cw[d*4+k]*bu2f(XZ[((size_t)(b*LSEQ+t2))*(2*DI) + d]);
  }
  XC[(size_t)tok*DI + d] = f2bu(silu_f(acc));
}

// ---------------- pack W_dt|W_B|W_C -> [2048][48] fp32 ----------------
__global__ void k_pack_wcat(const float* __restrict__ Wdt, const float* __restrict__ WB,
    const float* __restrict__ WC, float* __restrict__ WCAT){
  int idx = blockIdx.x*256+threadIdx.x;   // DI*48
  int k = idx/48, j = idx - k*48;
  float v;
  if(j<16)       v = Wdt[k*16+j];
  else if(j<32)  v = WB[k*16+j-16];
  else           v = WC[k*16+j-32];
  WCAT[idx] = v;
}

// ---------------- SB raw(dt_pre|Bm|Cm) -> (decay|dB|Cm) in place ----------------
__global__ void k_sbx(float* __restrict__ SB, const float* __restrict__ bdt,
                      const float* __restrict__ Av){
  int idx = blockIdx.x*256+threadIdx.x;   // NTOK*16
  int tok = idx>>4, n = idx&15;
  float* p = SB + (size_t)tok*48;
  float raw = p[n], bm = p[16+n];
  float v = raw + bdt[n];
  float dt = (v>20.f)? v : log1pf(__expf(v));
  p[n]    = __expf(dt*Av[n]);
  p[16+n] = dt*bm;
}

// ---------------- scan: per-chunk decay product ----------------
__global__ void k_scanP(const float* __restrict__ SB, float* __restrict__ P){
  int idx = blockIdx.x*256+threadIdx.x;   // 2*16*16 = 512
  if(idx>=512) return;
  int b = idx>>8, r = idx&255, c = r>>4, n = r&15;
  const float* base = SB + ((size_t)(b*LSEQ + c*128))*48 + n;
  float p = 1.f;
  for(int tt=0;tt<128;tt++) p *= base[(size_t)tt*48];
  P[(b*16+c)*16+n] = p;
}

// ---------------- scan phase A: within-chunk end state (h0=0) ----------------
__global__ __launch_bounds__(256) void k_scanA(const float* __restrict__ SB,
    const ushort* __restrict__ XC, float* __restrict__ E){
  __shared__ float sb[128*32];
  int t = threadIdx.x;
  int d = blockIdx.x*256 + t;
  int c = blockIdx.y, b = blockIdx.z;
  int tok0 = b*LSEQ + c*128;
  for(int i=0;i<16;i++){
    int fi = i*256 + t;
    int tt = fi>>5, j = fi&31;
    sb[fi] = SB[((size_t)(tok0+tt))*48 + j];
  }
  __syncthreads();
  float h[16];
  #pragma unroll
  for(int n=0;n<16;n++) h[n]=0.f;
  for(int tt=0;tt<128;tt++){
    float xv = bu2f(XC[((size_t)(tok0+tt))*DI + d]);
    const float* s = sb + tt*32;
    #pragma unroll
    for(int n=0;n<16;n++) h[n] = s[n]*h[n] + s[16+n]*xv;
  }
  float* e = E + (((size_t)(b*16+c)*DI) + d)*16;
  #pragma unroll
  for(int n=0;n<16;n++) e[n]=h[n];
}

// ---------------- scan carry across 16 chunks ----------------
__global__ void k_carry(const float* __restrict__ E, const float* __restrict__ P,
                        float* __restrict__ H0){
  int idx = blockIdx.x*256+threadIdx.x;   // 2*DI*16 = 65536
  int b = idx>>15, d = (idx>>4)&(DI-1), n = idx&15;
  float h = 0.f;
  for(int c=0;c<16;c++){
    size_t off = (((size_t)(b*16+c)*DI)+d)*16 + n;
    H0[off] = h;
    h = E[off] + P[(b*16+c)*16+n]*h;
  }
}

// ---------------- scan phase C: true h0, emit ym=(y+Dp*xc)*silu(z) into xm slots ------
__global__ __launch_bounds__(256) void k_scanC(const float* __restrict__ SB,
    const ushort* __restrict__ XC, ushort* __restrict__ AZ,
    const float* __restrict__ Dp, const float* __restrict__ H0){
  __shared__ float sb[128*48];
  int t = threadIdx.x;
  int d = blockIdx.x*256 + t;
  int c = blockIdx.y, b = blockIdx.z;
  int tok0 = b*LSEQ + c*128;
  for(int i=0;i<24;i++){
    int fi = i*256 + t;
    sb[fi] = SB[((size_t)tok0)*48 + fi];
  }
  __syncthreads();
  float h[16];
  const float* h0p = H0 + (((size_t)(b*16+c)*DI)+d)*16;
  #pragma unroll
  for(int n=0;n<16;n++) h[n]=h0p[n];
  float dpv = Dp[d];
  for(int tt=0;tt<128;tt++){
    size_t tok = (size_t)tok0+tt;
    float xv = bu2f(XC[tok*DI + d]);
    const float* s = sb + tt*48;
    #pragma unroll
    for(int n=0;n<16;n++) h[n] = s[n]*h[n] + s[16+n]*xv;
    float y = 0.f;
    #pragma unroll
    for(int n=0;n<16;n++) y += h[n]*s[32+n];
    y += dpv*xv;
    float z = bu2f(AZ[tok*(2*DI) + DI + d]);
    AZ[tok*(2*DI) + d] = f2bu(y*silu_f(z));   // ym overwrites dead xm slot
  }
}

// ---------------- rope tables (cos|sin)[t][128] fp32 ----------------
__global__ void k_rope_tab(float* __restrict__ R){
  int idx = blockIdx.x*256+threadIdx.x;   // LSEQ*64
  int tt = idx>>6, j = idx&63;
  double inv = pow(10000.0, -(double)j/64.0);
  double ph = (double)tt*inv;
  float c = (float)cos(ph), s = (float)sin(ph);
  float* r = R + (size_t)tt*256;
  r[j]=c; r[64+j]=c; r[128+j]=s; r[192+j]=s;
}

// ---------------- rope apply in place to q,k bf16 (q also * sqrt(128)) ----------------
__global__ __launch_bounds__(256) void k_rope_apply(ushort* __restrict__ QKV,
    const float* __restrict__ R){
  __shared__ float row[2048];
  int tok = blockIdx.x, t = threadIdx.x;
  ushort* qk = QKV + (size_t)tok*(3*DM);
  for(int i=0;i<2;i++){
    int fi = (i*256+t)*4;
    ushort4 v = *(const ushort4*)&qk[fi];
    row[fi]=bu2f(v.x); row[fi+1]=bu2f(v.y); row[fi+2]=bu2f(v.z); row[fi+3]=bu2f(v.w);
  }
  __syncthreads();
  int tt = tok & (LSEQ-1);
  const float* rt = R + (size_t)tt*256;
  for(int i=0;i<8;i++){
    int o = i*256 + t;
    int off = (o>=DM)?DM:0;
    int col = o & (DM-1);
    int h = col>>7, j = col&127;
    float base = row[o];
    float rot = (j<64)? -row[off + h*128 + 2*j+1] : row[off + h*128 + 2*(j-64)];
    float val = base*rt[j] + rot*rt[128+j];
    if(off==0) val *= 11.313708498984761f;   // sqrt(128)
    qk[o] = f2bu(val);
  }
}

// ---------------- fused attention, online softmax, 64 q-rows per block ----------------
__global__ __launch_bounds__(256) void k_attn(const ushort* __restrict__ QKV,
    const float* __restrict__ ascale, ushort* __restrict__ AO){
  __shared__ float Qs[64][129];
  __shared__ float Ks[64][128];
  __shared__ float Vs[64][128];
  __shared__ float S[64][65];
  __shared__ float mrow[64], lrow[64], crow[64];
  int t = threadIdx.x;
  int bh = blockIdx.y, b = bh>>3, h = bh&7;
  int qr0 = blockIdx.x<<6;
  size_t tokb = (size_t)b*LSEQ;
  float scale = ascale[h];
  for(int i=0;i<8;i++){
    int fi = i*256+t, r = fi>>5, c4 = (fi&31)<<2;
    const ushort* p = QKV + (tokb+qr0+r)*3*DM + h*DHD + c4;
    ushort4 v = *(const ushort4*)p;
    Qs[r][c4]=bu2f(v.x); Qs[r][c4+1]=bu2f(v.y); Qs[r][c4+2]=bu2f(v.z); Qs[r][c4+3]=bu2f(v.w);
  }
  if(t<64){ mrow[t]=-1e30f; lrow[t]=0.f; }
  float acc[32];
  #pragma unroll
  for(int j=0;j<32;j++) acc[j]=0.f;
  int rs = t&63, cg = t>>6;
  int rp = t>>2, d0 = (t&3)<<5;
  __syncthreads();
  for(int kt=0;kt<32;kt++){
    int kr0 = kt<<6;
    for(int i=0;i<8;i++){
      int fi = i*256+t, r = fi>>5, c4 = (fi&31)<<2;
      const ushort* pk = QKV + (tokb+kr0+r)*3*DM + DM   + h*DHD + c4;
      ushort4 kv = *(const ushort4*)pk;
      Ks[r][c4]=bu2f(kv.x); Ks[r][c4+1]=bu2f(kv.y); Ks[r][c4+2]=bu2f(kv.z); Ks[r][c4+3]=bu2f(kv.w);
      const ushort* pv = QKV + (tokb+kr0+r)*3*DM + 2*DM + h*DHD + c4;
      ushort4 vv = *(const ushort4*)pv;
      Vs[r][c4]=bu2f(vv.x); Vs[r][c4+1]=bu2f(vv.y); Vs[r][c4+2]=bu2f(vv.z); Vs[r][c4+3]=bu2f(vv.w);
    }
    __syncthreads();
    float sc[16];
    #pragma unroll
    for(int ci=0;ci<16;ci++) sc[ci]=0.f;
    for(int dd=0;dd<128;dd++){
      float qv = Qs[rs][dd];
      #pragma unroll
      for(int ci=0;ci<16;ci++) sc[ci] += qv*Ks[cg + (ci<<2)][dd];
    }
    #pragma unroll
    for(int ci=0;ci<16;ci++) S[rs][cg+(ci<<2)] = sc[ci]*scale;
    __syncthreads();
    if(t<64){
      float mo = mrow[t], mx = mo;
      for(int c=0;c<64;c++) mx = fmaxf(mx, S[t][c]);
      float co = __expf(mo-mx), sum=0.f;
      for(int c=0;c<64;c++){ float pp = __expf(S[t][c]-mx); S[t][c]=pp; sum+=pp; }
      mrow[t]=mx; lrow[t]=lrow[t]*co+sum; crow[t]=co;
    }
    __syncthreads();
    float co = crow[rp];
    #pragma unroll
    for(int j=0;j<32;j++) acc[j]*=co;
    for(int c=0;c<64;c++){
      float pp = S[rp][c];
      const float* vr = &Vs[c][d0];
      #pragma unroll
      for(int j=0;j<32;j++) acc[j] += pp*vr[j];
    }
    __syncthreads();
  }
  float inv = 1.f/lrow[rp];
  ushort* op = AO + (tokb+qr0+rp)*DM + h*DHD + d0;
  #pragma unroll
  for(int j=0;j<32;j++) op[j] = f2bu(acc[j]*inv);
}

// ---------------- gating logits: [4096][512] fp32 @ [512][4] ----------------
__global__ void k_logits(const float* __restrict__ G1, const float* __restrict__ Wg2,
                         float* __restrict__ LG){
  int tok = blockIdx.x*256+threadIdx.x;
  const float* g = G1 + (size_t)tok*512;
  float a0=0,a1=0,a2=0,a3=0;
  for(int k=0;k<512;k++){
    float gv = g[k];
    float4 w = *(const float4*)(Wg2 + k*4);
    a0 += gv*w.x; a1 += gv*w.y; a2 += gv*w.z; a3 += gv*w.w;
  }
  float* o = LG + (size_t)tok*4;
  o[0]=a0;o[1]=a1;o[2]=a2;o[3]=a3;
}

// ---------------- softmax + top2 weights + partial gm sums ----------------
__global__ __launch_bounds__(256) void k_gate(const float* __restrict__ LG,
    float* __restrict__ WTOK, float* __restrict__ PART){
  int t = threadIdx.x;
  int tok = blockIdx.x*256+t;
  float4 l = *(const float4*)(LG + (size_t)tok*4);
  float lv[4] = {l.x,l.y,l.z,l.w};
  float m = fmaxf(fmaxf(lv[0],lv[1]),fmaxf(lv[2],lv[3]));
  float e[4], s=0.f;
  #pragma unroll
  for(int i=0;i<4;i++){ e[i]=__expf(lv[i]-m); s+=e[i]; }
  float g[4];
  #pragma unroll
  for(int i=0;i<4;i++) g[i]=e[i]/s;
  int i1=0;
  #pragma unroll
  for(int i=1;i<4;i++) if(g[i]>g[i1]) i1=i;
  int i2=-1;
  #pragma unroll
  for(int i=0;i<4;i++){ if(i==i1) continue; if(i2<0||g[i]>g[i2]) i2=i; }
  float eb = __expf(g[i2]-g[i1]);
  float wa = 1.f/(1.f+eb), wb = eb/(1.f+eb);
  float w[4]={0.f,0.f,0.f,0.f}; w[i1]=wa; w[i2]=wb;
  *(float4*)(WTOK + (size_t)tok*4) = make_float4(w[0],w[1],w[2],w[3]);
  __shared__ float red[256];
  for(int ei=0; ei<4; ei++){
    red[t]=g[ei]; __syncthreads();
    for(int s2=128;s2>0;s2>>=1){ if(t<s2) red[t]+=red[t+s2]; __syncthreads(); }
    if(t==0) PART[blockIdx.x*4+ei]=red[0];
    __syncthreads();
  }
}

__global__ void k_bal(const float* __restrict__ PART, float* __restrict__ obal){
  if(threadIdx.x!=0 || blockIdx.x!=0) return;
  float gs[4]={0,0,0,0};
  for(int b=0;b<16;b++)
    for(int e=0;e<4;e++) gs[e]+=PART[b*4+e];
  float bal=0.f;
  for(int e=0;e<4;e++){ float gm = gs[e]/(float)NTOK; bal += gm*logf(gm+1e-8f); }
  obal[0] = (float)NEXP*bal;
}

extern "C" void kernel_launch(void* const* d_in, const int* in_sizes, int n_in,
                              void* d_out, int out_size, void* d_ws, size_t ws_size,
                              hipStream_t stream){
  const float* x    = (const float*)d_in[0];
  const float* r1w  = (const float*)d_in[1];
  const float* r2w  = (const float*)d_in[2];
  const float* r3w  = (const float*)d_in[3];
  const float* ls1  = (const float*)d_in[4];
  const float* ls2  = (const float*)d_in[5];
  const float* ls3  = (const float*)d_in[6];
  const float* Win  = (const float*)d_in[7];
  const float* convw= (const float*)d_in[8];
  const float* convb= (const float*)d_in[9];
  const float* WB   = (const float*)d_in[10];
  const float* WC   = (const float*)d_in[11];
  const float* Wdt  = (const float*)d_in[12];
  const float* bdt  = (const float*)d_in[13];
  const float* Woutm= (const float*)d_in[14];
  const float* Av   = (const float*)d_in[15];
  const float* Dp   = (const float*)d_in[16];
  const float* Wqkv = (const float*)d_in[17];
  const float* Wo   = (const float*)d_in[18];
  const float* ascl = (const float*)d_in[19];
  const float* Wg1  = (const float*)d_in[20];
  const float* bg1  = (const float*)d_in[21];
  const float* Wg2  = (const float*)d_in[22];
  const float* w1   = (const float*)d_in[23];
  const float* w2   = (const float*)d_in[24];
  const float* w3   = (const float*)d_in[25];
  float* out = (float*)d_out;
  float* ws  = (float*)d_ws;

  // ---- workspace layout (fp32 units), total 15,533,120 units = 62.1 MB ----
  ushort* AZ   = (ushort*)(ws + 0);         // 16,777,216 bf16: xm|z -> ym -> QKV -> MoE h
  ushort* XCb  = (ushort*)(ws + 8388608);   //  8,388,608 bf16: xc
  ushort* AOb  = (ushort*)(ws + 8388608);   //  4,194,304 bf16: attn out (first half of B)
  ushort* XNb  = (ushort*)(ws + 10485760);  //  4,194,304 bf16: rmsnorm out (second half of B)
  float*  SBp  = ws + 12582912;             //    196,608
  float*  E    = ws + 12779520;             //  1,048,576
  float*  H0   = ws + 13828096;             //  1,048,576
  float*  G1   = ws + 12779520;             //  2,097,152 (aliases E+H0, dead by MoE time)
  float*  P    = ws + 14876672;             //      1,024
  float*  WCAT = ws + 14877696;             //     98,304
  float*  ROPE = ws + 14976000;             //    524,288
  float*  LG   = ws + 15500288;             //     16,384
  float*  WTOK = ws + 15516672;             //     16,384
  float*  PART = ws + 15533056;             //         64

  // ---- Mamba sublayer ----
  k_rms<<<NTOK,256,0,stream>>>(x, r1w, XNb);
  k_gemm<ushort,0><<<dim3(64,64),256,0,stream>>>(XNb, Win, AZ, NTOK, 2*DI, DM, DM, nullptr, nullptr, 0);
  k_conv<<<(NTOK*DI)/256,256,0,stream>>>(AZ, convw, convb, XCb);
  k_pack_wcat<<<(DI*48)/256,256,0,stream>>>(Wdt, WB, WC, WCAT);
  k_gemm<float,0><<<dim3(1,64),256,0,stream>>>(XCb, WCAT, SBp, NTOK, 48, DI, DI, nullptr, nullptr, 0);
  k_sbx<<<(NTOK*DS)/256,256,0,stream>>>(SBp, bdt, Av);
  k_scanP<<<2,256,0,stream>>>(SBp, P);
  k_scanA<<<dim3(8,16,2),256,0,stream>>>(SBp, XCb, E);
  k_carry<<<(2*DI*DS)/256,256,0,stream>>>(E, P, H0);
  k_scanC<<<dim3(8,16,2),256,0,stream>>>(SBp, XCb, AZ, Dp, H0);
  k_gemm<float,1><<<dim3(16,64),256,0,stream>>>(AZ, Woutm, out, NTOK, DM, DI, 2*DI, x, ls1, 0);

  // ---- Attention sublayer ----
  k_rms<<<NTOK,256,0,stream>>>(out, r2w, XNb);
  k_gemm<ushort,0><<<dim3(48,64),256,0,stream>>>(XNb, Wqkv, AZ, NTOK, 3*DM, DM, DM, nullptr, nullptr, 0);
  k_rope_tab<<<(LSEQ*64)/256,256,0,stream>>>(ROPE);
  k_rope_apply<<<NTOK,256,0,stream>>>(AZ, ROPE);
  k_attn<<<dim3(32,16),256,0,stream>>>(AZ, ascl, AOb);
  k_gemm<float,2><<<dim3(16,64),256,0,stream>>>(AOb, Wo, out, NTOK, DM, DM, DM, nullptr, ls2, 0);

  // ---- MoE sublayer ----
  k_rms<<<NTOK,256,0,stream>>>(out, r3w, XNb);
  k_gemm<float,3><<<dim3(8,64),256,0,stream>>>(XNb, Wg1, G1, NTOK, 512, DM, DM, bg1, nullptr, 0);
  k_logits<<<NTOK/256,256,0,stream>>>(G1, Wg2, LG);
  k_gate<<<NTOK/256,256,0,stream>>>(LG, WTOK, PART);
  k_bal<<<1,64,0,stream>>>(PART, out + (size_t)NTOK*DM);
  for(int e=0;e<NEXP;e++){
    k_gemm2<<<dim3(64,64),256,0,stream>>>(XNb, w1 + (size_t)e*DM*DFF, w2 + (size_t)e*DM*DFF,
                                          AZ, NTOK, DFF, DM, DM);
    k_gemm<float,4><<<dim3(16,64),256,0,stream>>>(AZ, w3 + (size_t)e*DFF*DM, out,
                                                  NTOK, DM, DFF, DFF, WTOK, ls3, e);
  }
}

// Round 3
// 4606.502 us; speedup vs baseline: 2.1703x; 2.1703x over previous
//
#include <hip/hip_runtime.h>
#include <hip/hip_bf16.h>
#include <math.h>

#define NTOK 4096
#define DM   1024
#define DI   2048
#define DS   16
#define NH   8
#define DHD  128
#define NEXP 4
#define DFF  4096
#define LSEQ 2048
#define CHK  256
#define NCH  8

typedef float f32x4 __attribute__((ext_vector_type(4)));
typedef short bf16x8 __attribute__((ext_vector_type(8)));

static __device__ __forceinline__ float sigmoid_f(float x){ return 1.f/(1.f+__expf(-x)); }
static __device__ __forceinline__ float silu_f(float x){ return x*sigmoid_f(x); }
static __device__ __forceinline__ float bu2f(ushort u){ return __uint_as_float(((unsigned)u)<<16); }
static __device__ __forceinline__ ushort f2bu(float f){
  unsigned u = __float_as_uint(f);
  u += 0x7FFFu + ((u>>16)&1u);           // round-to-nearest-even
  return (ushort)(u>>16);
}
static __device__ __forceinline__ void stc(float* p, float v){ *p = v; }
static __device__ __forceinline__ void stc(ushort* p, float v){ *p = f2bu(v); }

// ---------------- RMSNorm: fp32 in -> bf16 out ----------------
__global__ __launch_bounds__(256) void k_rms(const float* __restrict__ x,
                                             const float* __restrict__ w,
                                             ushort* __restrict__ o){
  int tok = blockIdx.x, t = threadIdx.x;
  float4 v = *(const float4*)(x + (size_t)tok*DM + t*4);
  float ss = v.x*v.x+v.y*v.y+v.z*v.z+v.w*v.w;
  __shared__ float red[256];
  red[t]=ss; __syncthreads();
  for(int s=128;s>0;s>>=1){ if(t<s) red[t]+=red[t+s]; __syncthreads(); }
  float nrm = rsqrtf(red[0]*(1.f/DM)+1e-6f);
  float4 wv = *(const float4*)(w + t*4);
  ushort4 ov;
  ov.x=f2bu(v.x*nrm*wv.x); ov.y=f2bu(v.y*nrm*wv.y);
  ov.z=f2bu(v.z*nrm*wv.z); ov.w=f2bu(v.w*nrm*wv.w);
  *(ushort4*)(o + (size_t)tok*DM + t*4) = ov;
}

// ================= MFMA bf16 GEMM: 128x128 tile, BK=32, 4 waves =================
// A bf16 [M][lda], B fp32 [K][ldb] (converted to bf16 in staging), C [.][ldc]
// EPI 0: C(bf16)=acc | 1: C(f32)=aux1[idx]+aux2[col]*acc | 2: C(f32)+=aux2[col]*acc
// EPI 3: C(bf16)=silu(auxb[row*N+col])*acc | 4: C(f32)+=aux2[col]*aux1[row*4+eidx]*acc
template<int EPI, typename TC>
__global__ __launch_bounds__(256) void k_mg(
    const ushort* __restrict__ A, int lda,
    const float* __restrict__ B, int ldb,
    TC* __restrict__ C, int ldc,
    int N, int K,
    const float* __restrict__ aux1, const float* __restrict__ aux2,
    const ushort* __restrict__ auxb, int eidx){
  __shared__ ushort Al[128*32];
  __shared__ ushort Bl[128*32];
  int t = threadIdx.x;
  int lane = t & 63, w = t >> 6;
  int wr = w >> 1, wc = w & 1;
  int bm = blockIdx.y << 7, bn = blockIdx.x << 7;
  int lr = lane >> 4, lc = lane & 15;

  f32x4 acc[4][4];
  #pragma unroll
  for(int m=0;m<4;m++)
    #pragma unroll
    for(int n=0;n<4;n++) acc[m][n] = (f32x4){0.f,0.f,0.f,0.f};

  int arow = t >> 2, akc = (t & 3) << 3;     // A staging: 8 bf16 chunk
  int bcol = t >> 1, bks = (t & 1) << 4;     // B staging: 16 k per col

  uint4 aR[2];
  float bR[16];
  #pragma unroll
  for(int i=0;i<2;i++)
    aR[i] = *(const uint4*)(A + (size_t)(bm + arow + i*64)*lda + akc);
  #pragma unroll
  for(int j=0;j<16;j++)
    bR[j] = B[(size_t)(bks + j)*ldb + bn + bcol];

  for(int k0=0;k0<K;k0+=32){
    __syncthreads();
    #pragma unroll
    for(int i=0;i<2;i++){
      int row = arow + i*64;
      int idx = (row*32 + akc) ^ ((row&7)<<3);
      *(uint4*)&Al[idx] = aR[i];
    }
    {
      uint wds[8];
      #pragma unroll
      for(int i=0;i<8;i++)
        wds[i] = (uint)f2bu(bR[2*i]) | ((uint)f2bu(bR[2*i+1])<<16);
      int i1 = (bcol*32 + bks    ) ^ ((bcol&7)<<3);
      int i2 = (bcol*32 + bks + 8) ^ ((bcol&7)<<3);
      *(uint4*)&Bl[i1] = make_uint4(wds[0],wds[1],wds[2],wds[3]);
      *(uint4*)&Bl[i2] = make_uint4(wds[4],wds[5],wds[6],wds[7]);
    }
    __syncthreads();
    if(k0+32 < K){
      int kn = k0+32;
      #pragma unroll
      for(int i=0;i<2;i++)
        aR[i] = *(const uint4*)(A + (size_t)(bm + arow + i*64)*lda + kn + akc);
      #pragma unroll
      for(int j=0;j<16;j++)
        bR[j] = B[(size_t)(kn + bks + j)*ldb + bn + bcol];
    }
    bf16x8 af[4], bf[4];
    #pragma unroll
    for(int m=0;m<4;m++){
      int row = wr*64 + m*16 + lc;
      int idx = (row*32 + lr*8) ^ ((row&7)<<3);
      af[m] = *(bf16x8*)&Al[idx];
    }
    #pragma unroll
    for(int n=0;n<4;n++){
      int col = wc*64 + n*16 + lc;
      int idx = (col*32 + lr*8) ^ ((col&7)<<3);
      bf[n] = *(bf16x8*)&Bl[idx];
    }
    #pragma unroll
    for(int m=0;m<4;m++)
      #pragma unroll
      for(int n=0;n<4;n++)
        acc[m][n] = __builtin_amdgcn_mfma_f32_16x16x32_bf16(af[m], bf[n], acc[m][n], 0,0,0);
  }

  #pragma unroll
  for(int m=0;m<4;m++){
    int row0 = bm + wr*64 + m*16 + lr*4;
    #pragma unroll
    for(int n=0;n<4;n++){
      int col = bn + wc*64 + n*16 + lc;
      #pragma unroll
      for(int r=0;r<4;r++){
        int row = row0 + r;
        size_t idx = (size_t)row*ldc + col;
        float a = acc[m][n][r], val = a;
        if(EPI==1)      val = aux1[idx] + aux2[col]*a;
        else if(EPI==2) val = ((const float*)C)[idx] + aux2[col]*a;
        else if(EPI==3) val = silu_f(bu2f(auxb[(size_t)row*N + col])) * a;
        else if(EPI==4) val = ((const float*)C)[idx] + aux2[col]*aux1[(size_t)row*4+eidx]*a;
        stc(&C[idx], val);
      }
    }
  }
}

// ---------------- legacy small SIMT GEMM (N=48 / N=512 cases) ----------------
// EPI 0: C=acc | 3: C=relu(acc+aux1[col])
template<typename TC, int EPI>
__global__ __launch_bounds__(256) void k_gemm(const ushort* __restrict__ A,
    const float* __restrict__ B, TC* __restrict__ C,
    int M, int N, int K, int lda,
    const float* __restrict__ aux1){
  __shared__ float As[16][65];
  __shared__ float Bs[16][65];
  int t = threadIdx.x;
  int bm = blockIdx.y<<6, bn = blockIdx.x<<6;
  int tm = (t>>4)<<2, tn = (t&15)<<2;
  int ar = t>>2,  ak  = (t&3)<<2;
  int bk = t>>4,  bn4 = (t&15)<<2;
  float acc[4][4];
  #pragma unroll
  for(int i=0;i<4;i++)
    #pragma unroll
    for(int j=0;j<4;j++) acc[i][j]=0.f;
  for(int k0=0;k0<K;k0+=16){
    ushort4 av = *(const ushort4*)(A + (size_t)(bm+ar)*lda + k0 + ak);
    As[ak  ][ar]=bu2f(av.x); As[ak+1][ar]=bu2f(av.y);
    As[ak+2][ar]=bu2f(av.z); As[ak+3][ar]=bu2f(av.w);
    int col = bn + bn4;
    const float* bp = B + (size_t)(k0+bk)*N + col;
    float4 bv;
    if(col+3 < N){ bv = *(const float4*)bp; }
    else {
      bv.x=(col  <N)?bp[0]:0.f; bv.y=(col+1<N)?bp[1]:0.f;
      bv.z=(col+2<N)?bp[2]:0.f; bv.w=(col+3<N)?bp[3]:0.f;
    }
    Bs[bk][bn4]=bv.x; Bs[bk][bn4+1]=bv.y; Bs[bk][bn4+2]=bv.z; Bs[bk][bn4+3]=bv.w;
    __syncthreads();
    #pragma unroll
    for(int k=0;k<16;k++){
      float a0=As[k][tm],a1=As[k][tm+1],a2=As[k][tm+2],a3=As[k][tm+3];
      float b0=Bs[k][tn],b1=Bs[k][tn+1],b2=Bs[k][tn+2],b3=Bs[k][tn+3];
      acc[0][0]+=a0*b0; acc[0][1]+=a0*b1; acc[0][2]+=a0*b2; acc[0][3]+=a0*b3;
      acc[1][0]+=a1*b0; acc[1][1]+=a1*b1; acc[1][2]+=a1*b2; acc[1][3]+=a1*b3;
      acc[2][0]+=a2*b0; acc[2][1]+=a2*b1; acc[2][2]+=a2*b2; acc[2][3]+=a2*b3;
      acc[3][0]+=a3*b0; acc[3][1]+=a3*b1; acc[3][2]+=a3*b2; acc[3][3]+=a3*b3;
    }
    __syncthreads();
  }
  #pragma unroll
  for(int i=0;i<4;i++){
    int row = bm+tm+i;
    #pragma unroll
    for(int j=0;j<4;j++){
      int col = bn+tn+j;
      if(col>=N) continue;
      size_t idx = (size_t)row*N+col;
      float a = acc[i][j], val = a;
      if(EPI==3){ float s=a+aux1[col]; val = s>0.f?s:0.f; }
      stc(&C[idx], val);
    }
  }
}

// ---------------- depthwise conv (pad 2 left, 1 right) + SiLU ----------------
__global__ __launch_bounds__(256) void k_conv(const ushort* __restrict__ XZ,
    const float* __restrict__ cw, const float* __restrict__ cb,
    ushort* __restrict__ XC){
  int idx = blockIdx.x*256 + threadIdx.x;
  int d = idx & (DI-1);
  int tok = idx >> 11;
  int tt = tok & (LSEQ-1);
  int b = tok >> 11;
  float acc = cb[d];
  #pragma unroll
  for(int k=0;k<4;k++){
    int t2 = tt + k - 2;
    if((unsigned)t2 < LSEQ)
      acc += cw[d*4+k]*bu2f(XZ[((size_t)(b*LSEQ+t2))*(2*DI) + d]);
  }
  XC[(size_t)tok*DI + d] = f2bu(silu_f(acc));
}

// ---------------- pack W_dt|W_B|W_C -> [2048][48] fp32 ----------------
__global__ void k_pack_wcat(const float* __restrict__ Wdt, const float* __restrict__ WB,
    const float* __restrict__ WC, float* __restrict__ WCAT){
  int idx = blockIdx.x*256+threadIdx.x;
  int k = idx/48, j = idx - k*48;
  float v;
  if(j<16)       v = Wdt[k*16+j];
  else if(j<32)  v = WB[k*16+j-16];
  else           v = WC[k*16+j-32];
  WCAT[idx] = v;
}

// ---------------- SB raw(dt_pre|Bm|Cm) -> (decay|dB|Cm) in place ----------------
__global__ void k_sbx(float* __restrict__ SB, const float* __restrict__ bdt,
                      const float* __restrict__ Av){
  int idx = blockIdx.x*256+threadIdx.x;
  int tok = idx>>4, n = idx&15;
  float* p = SB + (size_t)tok*48;
  float raw = p[n], bm = p[16+n];
  float v = raw + bdt[n];
  float dt = (v>20.f)? v : log1pf(__expf(v));
  p[n]    = __expf(dt*Av[n]);
  p[16+n] = dt*bm;
}

// ---------------- scan: per-chunk decay product (CHK=256) ----------------
__global__ void k_scanP(const float* __restrict__ SB, float* __restrict__ P){
  int idx = threadIdx.x;                   // 2*8*16 = 256
  int b = idx>>7, r = idx&127, c = r>>4, n = r&15;
  const float* base = SB + ((size_t)(b*LSEQ + c*CHK))*48 + n;
  float p = 1.f;
  for(int tt=0;tt<CHK;tt++) p *= base[(size_t)tt*48];
  P[(b*NCH+c)*16+n] = p;
}

// ---------------- scan phase A: within-chunk end state (h0=0), E bf16 ----------------
__global__ __launch_bounds__(256) void k_scanA(const float* __restrict__ SB,
    const ushort* __restrict__ XC, ushort* __restrict__ E){
  __shared__ float sb[CHK*32];
  int t = threadIdx.x;
  int d = blockIdx.x*256 + t;
  int c = blockIdx.y, b = blockIdx.z;
  int tok0 = b*LSEQ + c*CHK;
  for(int i=0;i<32;i++){
    int fi = i*256 + t;
    int tt = fi>>5, j = fi&31;
    sb[fi] = SB[((size_t)(tok0+tt))*48 + j];
  }
  __syncthreads();
  float h[16];
  #pragma unroll
  for(int n=0;n<16;n++) h[n]=0.f;
  for(int tt=0;tt<CHK;tt++){
    float xv = bu2f(XC[((size_t)(tok0+tt))*DI + d]);
    const float* s = sb + tt*32;
    #pragma unroll
    for(int n=0;n<16;n++) h[n] = s[n]*h[n] + s[16+n]*xv;
  }
  ushort* e = E + (((size_t)(b*NCH+c)*DI) + d)*16;
  #pragma unroll
  for(int n=0;n<16;n++) e[n]=f2bu(h[n]);
}

// ---------------- scan carry across 8 chunks ----------------
__global__ void k_carry(const ushort* __restrict__ E, const float* __restrict__ P,
                        ushort* __restrict__ H0){
  int idx = blockIdx.x*256+threadIdx.x;   // 2*DI*16 = 65536
  int b = idx>>15, d = (idx>>4)&(DI-1), n = idx&15;
  float h = 0.f;
  for(int c=0;c<NCH;c++){
    size_t off = (((size_t)(b*NCH+c)*DI)+d)*16 + n;
    H0[off] = f2bu(h);
    h = bu2f(E[off]) + P[(b*NCH+c)*16+n]*h;
  }
}

// ---------------- scan phase C: true h0, emit ym into xm slots of AZ ------
__global__ __launch_bounds__(256) void k_scanC(const float* __restrict__ SB,
    const ushort* __restrict__ XC, ushort* __restrict__ AZ,
    const float* __restrict__ Dp, const ushort* __restrict__ H0){
  __shared__ float sb[CHK*48];
  int t = threadIdx.x;
  int d = blockIdx.x*256 + t;
  int c = blockIdx.y, b = blockIdx.z;
  int tok0 = b*LSEQ + c*CHK;
  for(int i=0;i<48;i++){
    int fi = i*256 + t;
    sb[fi] = SB[((size_t)tok0)*48 + fi];
  }
  __syncthreads();
  float h[16];
  const ushort* h0p = H0 + (((size_t)(b*NCH+c)*DI)+d)*16;
  #pragma unroll
  for(int n=0;n<16;n++) h[n]=bu2f(h0p[n]);
  float dpv = Dp[d];
  for(int tt=0;tt<CHK;tt++){
    size_t tok = (size_t)tok0+tt;
    float xv = bu2f(XC[tok*DI + d]);
    const float* s = sb + tt*48;
    #pragma unroll
    for(int n=0;n<16;n++) h[n] = s[n]*h[n] + s[16+n]*xv;
    float y = 0.f;
    #pragma unroll
    for(int n=0;n<16;n++) y += h[n]*s[32+n];
    y += dpv*xv;
    float z = bu2f(AZ[tok*(2*DI) + DI + d]);
    AZ[tok*(2*DI) + d] = f2bu(y*silu_f(z));
  }
}

// ---------------- rope tables (cos|sin)[t][128] fp32 ----------------
__global__ void k_rope_tab(float* __restrict__ R){
  int idx = blockIdx.x*256+threadIdx.x;   // LSEQ*64
  int tt = idx>>6, j = idx&63;
  double inv = pow(10000.0, -(double)j/64.0);
  double ph = (double)tt*inv;
  float c = (float)cos(ph), s = (float)sin(ph);
  float* r = R + (size_t)tt*256;
  r[j]=c; r[64+j]=c; r[128+j]=s; r[192+j]=s;
}

// ---------------- rope apply in place to q,k bf16 (q also * sqrt(128)) ----------------
__global__ __launch_bounds__(256) void k_rope_apply(ushort* __restrict__ QKV,
    const float* __restrict__ R){
  __shared__ float row[2048];
  int tok = blockIdx.x, t = threadIdx.x;
  ushort* qk = QKV + (size_t)tok*(3*DM);
  for(int i=0;i<2;i++){
    int fi = (i*256+t)*4;
    ushort4 v = *(const ushort4*)&qk[fi];
    row[fi]=bu2f(v.x); row[fi+1]=bu2f(v.y); row[fi+2]=bu2f(v.z); row[fi+3]=bu2f(v.w);
  }
  __syncthreads();
  int tt = tok & (LSEQ-1);
  const float* rt = R + (size_t)tt*256;
  for(int i=0;i<8;i++){
    int o = i*256 + t;
    int off = (o>=DM)?DM:0;
    int col = o & (DM-1);
    int h = col>>7, j = col&127;
    float base = row[o];
    float rot = (j<64)? -row[off + h*128 + 2*j+1] : row[off + h*128 + 2*(j-64)];
    float val = base*rt[j] + rot*rt[128+j];
    if(off==0) val *= 11.313708498984761f;   // sqrt(128)
    qk[o] = f2bu(val);
  }
}

// ---------------- fused attention, online softmax, 64 q-rows per block ----------------
__global__ __launch_bounds__(256) void k_attn(const ushort* __restrict__ QKV,
    const float* __restrict__ ascale, ushort* __restrict__ AO){
  __shared__ float Qs[64][129];
  __shared__ float Ks[64][128];
  __shared__ float Vs[64][129];
  __shared__ float S[64][65];
  __shared__ float mrow[64], lrow[64], crow[64];
  int t = threadIdx.x;
  int bh = blockIdx.y, b = bh>>3, h = bh&7;
  int qr0 = blockIdx.x<<6;
  size_t tokb = (size_t)b*LSEQ;
  float scale = ascale[h];
  for(int i=0;i<8;i++){
    int fi = i*256+t, r = fi>>5, c4 = (fi&31)<<2;
    const ushort* p = QKV + (tokb+qr0+r)*3*DM + h*DHD + c4;
    ushort4 v = *(const ushort4*)p;
    Qs[r][c4]=bu2f(v.x); Qs[r][c4+1]=bu2f(v.y); Qs[r][c4+2]=bu2f(v.z); Qs[r][c4+3]=bu2f(v.w);
  }
  if(t<64){ mrow[t]=-1e30f; lrow[t]=0.f; }
  float acc[32];
  #pragma unroll
  for(int j=0;j<32;j++) acc[j]=0.f;
  int rs = t&63, cg = t>>6;
  int rp = t>>2, d0 = (t&3)<<5;
  int cro = (t&3)<<4;                 // per-group c rotation (bank spread)
  __syncthreads();
  for(int kt=0;kt<32;kt++){
    int kr0 = kt<<6;
    for(int i=0;i<8;i++){
      int fi = i*256+t, r = fi>>5, c4 = (fi&31)<<2;
      const ushort* pk = QKV + (tokb+kr0+r)*3*DM + DM   + h*DHD + c4;
      ushort4 kv = *(const ushort4*)pk;
      Ks[r][c4]=bu2f(kv.x); Ks[r][c4+1]=bu2f(kv.y); Ks[r][c4+2]=bu2f(kv.z); Ks[r][c4+3]=bu2f(kv.w);
      const ushort* pv = QKV + (tokb+kr0+r)*3*DM + 2*DM + h*DHD + c4;
      ushort4 vv = *(const ushort4*)pv;
      Vs[r][c4]=bu2f(vv.x); Vs[r][c4+1]=bu2f(vv.y); Vs[r][c4+2]=bu2f(vv.z); Vs[r][c4+3]=bu2f(vv.w);
    }
    __syncthreads();
    float sc[16];
    #pragma unroll
    for(int ci=0;ci<16;ci++) sc[ci]=0.f;
    for(int dd=0;dd<128;dd++){
      float qv = Qs[rs][dd];
      #pragma unroll
      for(int ci=0;ci<16;ci++) sc[ci] += qv*Ks[cg + (ci<<2)][dd];
    }
    #pragma unroll
    for(int ci=0;ci<16;ci++) S[rs][cg+(ci<<2)] = sc[ci]*scale;
    __syncthreads();
    if(t<64){
      float mo = mrow[t], mx = mo;
      for(int c=0;c<64;c++) mx = fmaxf(mx, S[t][c]);
      float co = __expf(mo-mx), sum=0.f;
      for(int c=0;c<64;c++){ float pp = __expf(S[t][c]-mx); S[t][c]=pp; sum+=pp; }
      mrow[t]=mx; lrow[t]=lrow[t]*co+sum; crow[t]=co;
    }
    __syncthreads();
    float co = crow[rp];
    #pragma unroll
    for(int j=0;j<32;j++) acc[j]*=co;
    for(int cc=0;cc<64;cc++){
      int c = (cc + cro) & 63;
      float pp = S[rp][c];
      const float* vr = &Vs[c][d0];
      #pragma unroll
      for(int j=0;j<32;j++) acc[j] += pp*vr[j];
    }
    __syncthreads();
  }
  float inv = 1.f/lrow[rp];
  ushort* op = AO + (tokb+qr0+rp)*DM + h*DHD + d0;
  #pragma unroll
  for(int j=0;j<32;j++) op[j] = f2bu(acc[j]*inv);
}

// ---------------- gating logits: [4096][512] fp32 @ [512][4] ----------------
__global__ void k_logits(const float* __restrict__ G1, const float* __restrict__ Wg2,
                         float* __restrict__ LG){
  int tok = blockIdx.x*256+threadIdx.x;
  const float* g = G1 + (size_t)tok*512;
  float a0=0,a1=0,a2=0,a3=0;
  for(int k=0;k<512;k++){
    float gv = g[k];
    float4 w = *(const float4*)(Wg2 + k*4);
    a0 += gv*w.x; a1 += gv*w.y; a2 += gv*w.z; a3 += gv*w.w;
  }
  float* o = LG + (size_t)tok*4;
  o[0]=a0;o[1]=a1;o[2]=a2;o[3]=a3;
}

// ---------------- softmax + top2 weights + partial gm sums ----------------
__global__ __launch_bounds__(256) void k_gate(const float* __restrict__ LG,
    float* __restrict__ WTOK, float* __restrict__ PART){
  int t = threadIdx.x;
  int tok = blockIdx.x*256+t;
  float4 l = *(const float4*)(LG + (size_t)tok*4);
  float lv[4] = {l.x,l.y,l.z,l.w};
  float m = fmaxf(fmaxf(lv[0],lv[1]),fmaxf(lv[2],lv[3]));
  float e[4], s=0.f;
  #pragma unroll
  for(int i=0;i<4;i++){ e[i]=__expf(lv[i]-m); s+=e[i]; }
  float g[4];
  #pragma unroll
  for(int i=0;i<4;i++) g[i]=e[i]/s;
  int i1=0;
  #pragma unroll
  for(int i=1;i<4;i++) if(g[i]>g[i1]) i1=i;
  int i2=-1;
  #pragma unroll
  for(int i=0;i<4;i++){ if(i==i1) continue; if(i2<0||g[i]>g[i2]) i2=i; }
  float eb = __expf(g[i2]-g[i1]);
  float wa = 1.f/(1.f+eb), wb = eb/(1.f+eb);
  float w[4]={0.f,0.f,0.f,0.f}; w[i1]=wa; w[i2]=wb;
  *(float4*)(WTOK + (size_t)tok*4) = make_float4(w[0],w[1],w[2],w[3]);
  __shared__ float red[256];
  for(int ei=0; ei<4; ei++){
    red[t]=g[ei]; __syncthreads();
    for(int s2=128;s2>0;s2>>=1){ if(t<s2) red[t]+=red[t+s2]; __syncthreads(); }
    if(t==0) PART[blockIdx.x*4+ei]=red[0];
    __syncthreads();
  }
}

__global__ void k_bal(const float* __restrict__ PART, float* __restrict__ obal){
  if(threadIdx.x!=0 || blockIdx.x!=0) return;
  float gs[4]={0,0,0,0};
  for(int b=0;b<16;b++)
    for(int e=0;e<4;e++) gs[e]+=PART[b*4+e];
  float bal=0.f;
  for(int e=0;e<4;e++){ float gm = gs[e]/(float)NTOK; bal += gm*logf(gm+1e-8f); }
  obal[0] = (float)NEXP*bal;
}

extern "C" void kernel_launch(void* const* d_in, const int* in_sizes, int n_in,
                              void* d_out, int out_size, void* d_ws, size_t ws_size,
                              hipStream_t stream){
  const float* x    = (const float*)d_in[0];
  const float* r1w  = (const float*)d_in[1];
  const float* r2w  = (const float*)d_in[2];
  const float* r3w  = (const float*)d_in[3];
  const float* ls1  = (const float*)d_in[4];
  const float* ls2  = (const float*)d_in[5];
  const float* ls3  = (const float*)d_in[6];
  const float* Win  = (const float*)d_in[7];
  const float* convw= (const float*)d_in[8];
  const float* convb= (const float*)d_in[9];
  const float* WB   = (const float*)d_in[10];
  const float* WC   = (const float*)d_in[11];
  const float* Wdt  = (const float*)d_in[12];
  const float* bdt  = (const float*)d_in[13];
  const float* Woutm= (const float*)d_in[14];
  const float* Av   = (const float*)d_in[15];
  const float* Dp   = (const float*)d_in[16];
  const float* Wqkv = (const float*)d_in[17];
  const float* Wo   = (const float*)d_in[18];
  const float* ascl = (const float*)d_in[19];
  const float* Wg1  = (const float*)d_in[20];
  const float* bg1  = (const float*)d_in[21];
  const float* Wg2  = (const float*)d_in[22];
  const float* w1   = (const float*)d_in[23];
  const float* w2   = (const float*)d_in[24];
  const float* w3   = (const float*)d_in[25];
  float* out = (float*)d_out;
  char*  wsb = (char*)d_ws;

  // ---- workspace layout (bytes), total 62,129,408 B ----
  ushort* AZ   = (ushort*)(wsb);                 // 33,554,432: xm|z -> ym -> QKV -> h
  ushort* BUF1 = (ushort*)(wsb + 33554432);      // 16,777,216: xc / AO+G1 / T(half h1)
  ushort* XNb  = (ushort*)(wsb + 50331648);      //  8,388,608: rmsnorm outs
  float*  SBp  = (float*) (wsb + 58720256);      //    786,432
  ushort* E    = (ushort*)(wsb + 59506688);      //  1,048,576
  ushort* H0   = (ushort*)(wsb + 60555264);      //  1,048,576
  float*  ROPE = (float*) (wsb + 59506688);      //  2,097,152 (alias E+H0)
  float*  P    = (float*) (wsb + 61603840);      //      1,024
  float*  WCAT = (float*) (wsb + 61604864);      //    393,216
  float*  LG   = (float*) (wsb + 61998080);      //     65,536
  float*  WTOK = (float*) (wsb + 62063616);      //     65,536
  float*  PART = (float*) (wsb + 62129152);      //        256
  ushort* XCb = BUF1;
  ushort* AOb = BUF1;
  float*  G1  = (float*)BUF1;
  ushort* T   = BUF1;

  // ---- Mamba sublayer ----
  k_rms<<<NTOK,256,0,stream>>>(x, r1w, XNb);
  k_mg<0,ushort><<<dim3(32,32),256,0,stream>>>(XNb, DM, Win, 2*DI, AZ, 2*DI, 2*DI, DM, nullptr, nullptr, nullptr, 0);
  k_conv<<<(NTOK*DI)/256,256,0,stream>>>(AZ, convw, convb, XCb);
  k_pack_wcat<<<(DI*48)/256,256,0,stream>>>(Wdt, WB, WC, WCAT);
  k_gemm<float,0><<<dim3(1,64),256,0,stream>>>(XCb, WCAT, SBp, NTOK, 48, DI, DI, nullptr);
  k_sbx<<<(NTOK*DS)/256,256,0,stream>>>(SBp, bdt, Av);
  k_scanP<<<1,256,0,stream>>>(SBp, P);
  k_scanA<<<dim3(8,NCH,2),256,0,stream>>>(SBp, XCb, E);
  k_carry<<<(2*DI*DS)/256,256,0,stream>>>(E, P, H0);
  k_scanC<<<dim3(8,NCH,2),256,0,stream>>>(SBp, XCb, AZ, Dp, H0);
  k_mg<1,float><<<dim3(8,32),256,0,stream>>>(AZ, 2*DI, Woutm, DM, out, DM, DM, DI, x, ls1, nullptr, 0);

  // ---- Attention sublayer ----
  k_rms<<<NTOK,256,0,stream>>>(out, r2w, XNb);
  k_mg<0,ushort><<<dim3(24,32),256,0,stream>>>(XNb, DM, Wqkv, 3*DM, AZ, 3*DM, 3*DM, DM, nullptr, nullptr, nullptr, 0);
  k_rope_tab<<<(LSEQ*64)/256,256,0,stream>>>(ROPE);
  k_rope_apply<<<NTOK,256,0,stream>>>(AZ, ROPE);
  k_attn<<<dim3(32,16),256,0,stream>>>(AZ, ascl, AOb);
  k_mg<2,float><<<dim3(8,32),256,0,stream>>>(AOb, DM, Wo, DM, out, DM, DM, DM, nullptr, ls2, nullptr, 0);

  // ---- MoE sublayer ----
  k_rms<<<NTOK,256,0,stream>>>(out, r3w, XNb);
  k_gemm<float,3><<<dim3(8,64),256,0,stream>>>(XNb, Wg1, G1, NTOK, 512, DM, DM, bg1);
  k_logits<<<NTOK/256,256,0,stream>>>(G1, Wg2, LG);
  k_gate<<<NTOK/256,256,0,stream>>>(LG, WTOK, PART);
  k_bal<<<1,64,0,stream>>>(PART, out + (size_t)NTOK*DM);
  for(int e=0;e<NEXP;e++){
    for(int half=0; half<2; ++half){
      const float* w1p = w1 + (size_t)e*DM*DFF + half*2048;
      const float* w2p = w2 + (size_t)e*DM*DFF + half*2048;
      k_mg<0,ushort><<<dim3(16,32),256,0,stream>>>(XNb, DM, w1p, DFF, T, 2048, 2048, DM, nullptr, nullptr, nullptr, 0);
      k_mg<3,ushort><<<dim3(16,32),256,0,stream>>>(XNb, DM, w2p, DFF, AZ + half*2048, DFF, 2048, DM, nullptr, nullptr, T, 0);
    }
    k_mg<4,float><<<dim3(8,32),256,0,stream>>>(AZ, DFF, w3 + (size_t)e*DFF*DM, DM, out, DM, DM, DFF, WTOK, ls3, nullptr, e);
  }
}